// Round 13
// baseline (130.927 us; speedup 1.0000x reference)
//
#include <hip/hip_runtime.h>
#include <stdint.h>
#include <math.h>

// Validated semantics (r17/r18 green): printed reference, fp32 in/out.
//   p[b,j] = mean_h sigmoid(delta/sqrt(32)),
//   delta[j,b,h] = sum_e D_e*(U+V),  D_e = (s_e-mu_s)-(o_e-mu_o)
//   Folded mu: sum_e D*w = sum_e (s-o)*w - ((sum s - sum o)/256)*sum_e w
//   U[h,e,j] = sum_{d in h} QwT[d,j]*Wk[d,e],  QwT = Qp[256+j]@Wq^T
//   V[b,h,e] = sum_{d in h} (Pq[b,d]+bq[d])*Wk[d,e],  Pq = pe[b]@Wq^T
//   new_state[b,e,l<256]=state; l>=256: p*s_l+(1-p)*o_{l-256} = o + p*(s-o)
//   atten[b,l,s]: l<256 -> 1 at s=l; else p at s=l, 1-p at s=l+256.
// This round: fuse k_qw+k_uv into ONE kernel (3 launches -> 2). U-block
// (h, j-tile32) computes its QwT 32x32 tile in-LDS (same tiling as the
// verified r12 k_qw), then contracts with LDS-staged Wk chunks -> U.
// V-block (b,h) computes pe analytically, reduces Pq[32] in-block, then
// streams Wk (r6 V-half). QwT/Pq never hit global. k_delta identical to r12
// (117.99us build).

// d_ws layout (floats) — only U and V used now
#define WS_U    81920    // [8 h][256 e][256 j]
#define WS_V    606208   // [32 b][8 h][256 e]

typedef float vf4 __attribute__((ext_vector_type(4)));
__device__ __forceinline__ void nt_store4(float* p, float x, float y,
                                          float z, float w) {
  vf4 v; v.x = x; v.y = y; v.z = z; v.w = w;
  __builtin_nontemporal_store(v, (vf4*)p);
}

// ---------------------------------------------------------------------------
// K1: U (64 blocks: h, j-tile32) + V (256 blocks: b,h). 320 blocks x 256.
__global__ void __launch_bounds__(256)
k_uvw(const float* __restrict__ Qp, const float* __restrict__ Wq,
      const float* __restrict__ Wk, const float* __restrict__ bq,
      float* __restrict__ ws) {
  __shared__ float A[9504];             // 38 KB arena
  int bid = blockIdx.x, t = threadIdx.x;
  if (bid < 64) {                       // ---- U-path ----
    int h = bid >> 3, j0 = (bid & 7) << 5;
    int d0 = h << 5;
    float* wq_s  = A;                   // [32][132] (phase 1; reused as wk_s)
    float* qp_s  = A + 4224;            // [32][132] (phase 1)
    float* qwt_s = A + 8448;            // [32][33]
    int j = t & 31, dq = t >> 5;        // thread: j, d = d0+dq*4..+3
    float acc[4] = {0.f, 0.f, 0.f, 0.f};
    // Phase 1: QwT[d][j] tile (identical tiling to r12 k_qw)
    for (int ec = 0; ec < 256; ec += 128) {
      #pragma unroll
      for (int k = 0; k < 4; ++k) {     // stage both tiles, f4 coalesced
        int i = (k << 8) + t;           // 0..1023
        int r = i >> 5, c4 = i & 31;    // row, f4-col of 128-float chunk
        *(float4*)&wq_s[r * 132 + (c4 << 2)] =
            *(const float4*)(Wq + (size_t)(d0 + r) * 256 + ec + (c4 << 2));
        *(float4*)&qp_s[r * 132 + (c4 << 2)] =
            *(const float4*)(Qp + 65536 + (size_t)(j0 + r) * 256 + ec + (c4 << 2));
      }
      __syncthreads();
      #pragma unroll 8
      for (int e4 = 0; e4 < 32; ++e4) {
        float4 q = *(const float4*)&qp_s[j * 132 + (e4 << 2)];
        #pragma unroll
        for (int r = 0; r < 4; ++r) {
          float4 w = *(const float4*)&wq_s[((dq << 2) + r) * 132 + (e4 << 2)];
          acc[r] += w.x * q.x + w.y * q.y + w.z * q.z + w.w * q.w;
        }
      }
      __syncthreads();
    }
    #pragma unroll
    for (int r = 0; r < 4; ++r)
      qwt_s[((dq << 2) + r) * 33 + j] = acc[r];
    __syncthreads();
    // Phase 2: U[h][e][j0+j] = sum_d qwt_s[d][j] * Wk[d0+d][e], e-chunks 128
    float* wk_s = A;                    // reuse phase-1 wq_s slot
    for (int ec = 0; ec < 256; ec += 128) {
      #pragma unroll
      for (int k = 0; k < 4; ++k) {     // stage Wk chunk
        int i = (k << 8) + t;
        int r = i >> 5, c4 = i & 31;
        *(float4*)&wk_s[r * 132 + (c4 << 2)] =
            *(const float4*)(Wk + (size_t)(d0 + r) * 256 + ec + (c4 << 2));
      }
      __syncthreads();
      int es8 = t >> 5;                 // e_local = es8 + 8k
      float* Uh = ws + WS_U + (h << 16) + j0 + j;
      #pragma unroll
      for (int k = 0; k < 16; ++k) {
        int el = es8 + (k << 3);
        float u = 0.f;
        #pragma unroll
        for (int d = 0; d < 32; ++d)
          u += qwt_s[d * 33 + j] * wk_s[d * 132 + el];
        Uh[(size_t)(ec + el) << 8] = u;
      }
      __syncthreads();
    }
  } else {                              // ---- V-path (b,h) ----
    int idx = bid - 64, b = idx >> 3, h = idx & 7;
    float* pe_s = A;                    // [256]
    float* psum = A + 256;              // [32][9] padded
    float* pq_s = A + 544;              // [32]
    {                                   // pe[b][c] analytic
      int k2 = t & ~1;                  // arange value 2k
      float div = expf((float)k2 * (-9.210340371976184f / 256.f));
      float a = (float)b * div;
      pe_s[t] = (t & 1) ? cosf(a) : sinf(a);
    }
    __syncthreads();
    {                                   // Pq partials: (d8 = t>>3, c8 = t&7)
      int d8 = t >> 3, c8 = t & 7;
      const float* wrow = Wq + (size_t)((h << 5) + d8) * 256 + (c8 << 5);
      const float* prow = pe_s + (c8 << 5);
      float part = 0.f;
      #pragma unroll
      for (int i = 0; i < 8; ++i) {
        float4 w4 = *(const float4*)(wrow + (i << 2));
        float4 p4 = *(const float4*)(prow + (i << 2));
        part += w4.x * p4.x + w4.y * p4.y + w4.z * p4.z + w4.w * p4.w;
      }
      psum[d8 * 9 + c8] = part;
    }
    __syncthreads();
    if (t < 32) {                       // reduce 8 partials + bq
      float s = bq[(h << 5) + t];
      #pragma unroll
      for (int c8 = 0; c8 < 8; ++c8) s += psum[t * 9 + c8];
      pq_s[t] = s;
    }
    __syncthreads();
    float acc = 0.f;                    // V[e=t] = sum_d pq[d]*Wk[d][t]
    #pragma unroll 8
    for (int dd = 0; dd < 32; ++dd)
      acc += pq_s[dd] * Wk[(size_t)((h << 5) + dd) * 256 + t];
    ws[WS_V + ((b << 3) + h) * 256 + t] = acc;
  }
}

// ---------------------------------------------------------------------------
// K2: delta + ALL output. 14592 blocks x 256. (r12 version, unchanged)
//   [0,256):        delta compute (b, j-tile32) + merge cols + atten diag
//   [256,2304):     new_state identity half (state cols 0..255)
//   [2304,14592):   atten static (one-hot l<256; zeros l>=256 minus diag f4s)
__global__ void __launch_bounds__(256)
k_delta(const float* __restrict__ state, const float* __restrict__ obs,
        float* __restrict__ ws, float* __restrict__ out) {
  int bid = blockIdx.x, t = threadIdx.x;
  if (bid < 256) {
    int b = bid >> 3, jt = (bid & 7) << 5;
    __shared__ float Xs[256][33];       // X[e][j], +1 pad -> <=2-way (free)
    __shared__ float Vs[2048];          // V[b][h][e] slice
    __shared__ float pd[8][8][32];      // [eg][h][j] partial sum X*w
    __shared__ float pw[8][8][32];      // [eg][h][j] partial sum w
    __shared__ float px[8][32];         // [eg][j]    partial sum X (reused)
    __shared__ float pfin[32];          // final p[b, jt+j]
    {                                   // stage: (es 0..31, jq 0..7) float4
      int es = t >> 3, jq = t & 7;
      const float* sp = state + (size_t)b * 131072 + 256 + jt + (jq << 2);
      const float* op = obs   + (size_t)b * 65536  + jt + (jq << 2);
      #pragma unroll
      for (int k = 0; k < 8; ++k) {
        int e = es + (k << 5);
        float4 s4 = *(const float4*)(sp + (size_t)e * 512);
        float4 o4 = *(const float4*)(op + (size_t)e * 256);
        float* xr = &Xs[e][jq << 2];
        xr[0] = s4.x - o4.x; xr[1] = s4.y - o4.y;
        xr[2] = s4.z - o4.z; xr[3] = s4.w - o4.w;
      }
      for (int i = t; i < 2048; i += 256) Vs[i] = ws[WS_V + (b << 11) + i];
    }
    __syncthreads();
    int j = t & 31, eg = t >> 5, e0 = eg << 5;
    {                                   // a_x partial (h-independent)
      float ax = 0.f;
      #pragma unroll
      for (int ei = 0; ei < 32; ++ei) ax += Xs[e0 + ei][j];
      px[eg][j] = ax;
    }
    const float* __restrict__ Ub = ws + WS_U + jt + j;
    #pragma unroll
    for (int h = 0; h < 8; ++h) {
      float dacc = 0.f, wacc = 0.f;
      const float* __restrict__ Uh = Ub + (h << 16) + (e0 << 8);
      const float* __restrict__ Vh = Vs + (h << 8) + e0;
      #pragma unroll 16
      for (int ei = 0; ei < 32; ++ei) {
        float w = Uh[ei << 8] + Vh[ei];
        dacc += Xs[e0 + ei][j] * w;
        wacc += w;
      }
      pd[eg][h][j] = dacc;
      pw[eg][h][j] = wacc;
    }
    __syncthreads();
    int h2 = t >> 5, j2 = t & 31;       // thread -> (h, j) for the merge
    float D = 0.f, W = 0.f, X = 0.f;
    #pragma unroll
    for (int g = 0; g < 8; ++g) {
      D += pd[g][h2][j2];
      W += pw[g][h2][j2];
      X += px[g][j2];
    }
    float delta = D - X * (1.f / 256.f) * W;
    float sig = 1.f / (1.f + __expf(-delta * 0.17677669529663687f)); // /sqrt(32)
    __syncthreads();
    px[h2][j2] = sig;                   // reuse px as [h][j] sigmoid buffer
    __syncthreads();
    if (t < 32) {
      float acc = 0.f;
      #pragma unroll
      for (int h = 0; h < 8; ++h) acc += px[h][t];
      float p = acc * 0.125f;
      pfin[t] = p;
      // atten diagonal: row l = 256+jt+t, f4 c1 = l>>2 (s=l), c2 = c1+64
      int l = 256 + jt + t;
      size_t rb = 4194304 + (size_t)((b << 9) + l) * 768;
      int c1 = l >> 2, pos = l & 3;
      float v1[4] = {0.f, 0.f, 0.f, 0.f}; v1[pos] = p;
      nt_store4(out + rb + (c1 << 2), v1[0], v1[1], v1[2], v1[3]);
      float v2[4] = {0.f, 0.f, 0.f, 0.f}; v2[pos] = 1.f - p;
      nt_store4(out + rb + ((c1 + 64) << 2), v2[0], v2[1], v2[2], v2[3]);
    }
    __syncthreads();
    // Fused merge: new_state[b, e, 256+jt+j] = o + p*X.
    {
      int eb = t >> 3, j0 = (t & 7) << 2;
      const float* op2 = obs + (size_t)b * 65536 + jt + j0;
      float p0 = pfin[j0], p1 = pfin[j0 + 1], p2 = pfin[j0 + 2], p3 = pfin[j0 + 3];
      float* orow = out + (size_t)b * 131072 + 256 + jt + j0;
      #pragma unroll
      for (int k = 0; k < 8; ++k) {
        int e = eb + (k << 5);
        float4 o4 = *(const float4*)(op2 + (size_t)e * 256);
        const float* xr = &Xs[e][j0];
        nt_store4(orow + (size_t)e * 512,
                  o4.x + p0 * xr[0], o4.y + p1 * xr[1],
                  o4.z + p2 * xr[2], o4.w + p3 * xr[3]);
      }
    }
  } else if (bid < 2304) {              // new_state[b,e,0..255] = state
    int row = ((bid - 256) << 2) | (t >> 6);  // row = b*256 + e
    int c = t & 63;                     // f4 col in lower half
    float4 sv = ((const float4*)(state + (size_t)row * 512))[c];
    nt_store4(out + (size_t)row * 512 + (c << 2), sv.x, sv.y, sv.z, sv.w);
  } else {                              // atten static, one float4 per thread
    int g4 = (bid - 2304) * 256 + t;    // 0..3145727
    int r = g4 / 192, c = g4 - r * 192; // r = b*512 + l
    int b = r >> 9, l = r & 511;
    int s0 = c << 2;
    if (l < 256) {                      // one-hot at s=l (P-independent)
      float v[4] = {0.f, 0.f, 0.f, 0.f};
      if (l >= s0 && l < s0 + 4) v[l - s0] = 1.0f;
      nt_store4(out + 4194304 + ((size_t)g4 << 2), v[0], v[1], v[2], v[3]);
    } else {                            // zeros, skipping the 2 diag f4s
      int c1 = l >> 2;                  // s=l f4 (64..127); c2 = c1+64
      if (c != c1 && c != c1 + 64)
        nt_store4(out + 4194304 + ((size_t)g4 << 2), 0.f, 0.f, 0.f, 0.f);
    }
  }
}

extern "C" void kernel_launch(void* const* d_in, const int* in_sizes, int n_in,
                              void* d_out, int out_size, void* d_ws, size_t ws_size,
                              hipStream_t stream) {
  const float *state = nullptr, *obs = nullptr, *Qp = nullptr;
  const float *Wq = nullptr, *Wk = nullptr, *bq = nullptr, *bk = nullptr;
  for (int i = 0; i < n_in; ++i) {
    int s = in_sizes[i];
    const float* p = (const float*)d_in[i];
    if      (s == 4194304) state = p;
    else if (s == 2097152) obs = p;
    else if (s == 131072)  Qp = p;
    else if (s == 65536)   { if (!Wq) Wq = p; else Wk = p; }
    else if (s == 256)     { if (!bq) bq = p; else bk = p; }
  }
  (void)bk;                             // cancels in the 2-way softmax
  float* out = (float*)d_out;
  float* ws  = (float*)d_ws;

  k_uvw  <<<320,   256, 0, stream>>>(Qp, Wq, Wk, bq, ws);
  k_delta<<<14592, 256, 0, stream>>>(state, obs, ws, out);
}

// Round 14
// 119.565 us; speedup vs baseline: 1.0950x; 1.0950x over previous
//
#include <hip/hip_runtime.h>
#include <stdint.h>
#include <math.h>

// Validated semantics (r17/r18 green): printed reference, fp32 in/out.
//   p[b,j] = mean_h sigmoid(delta/sqrt(32)),
//   delta[j,b,h] = sum_e D_e*(U+V),  D_e = (s_e-mu_s)-(o_e-mu_o)
//   Folded mu: sum_e D*w = sum_e (s-o)*w - ((sum s - sum o)/256)*sum_e w
//   U[h,e,j] = sum_{d in h} QwT[d,j]*Wk[d,e],  QwT = Qp[256+j]@Wq^T
//   V[b,h,e] = sum_{d in h} (Pq[b,d]+bq[d])*Wk[d,e],  Pq = pe[b]@Wq^T
//   new_state[b,e,l<256]=state; l>=256: p*s_l+(1-p)*o_{l-256} = o + p*(s-o)
//   atten[b,l,s]: l<256 -> 1 at s=l; else p at s=l, 1-p at s=l+256.
// r13 post-mortem: in-kernel QwT recompute made U-production 64-block +
// LDS-scalar-bound (~1024 ds_read_b32/thread, 1 block/CU) -> regression.
// The 2MB QwT L2 round-trip between well-parallelized kernels is cheaper.
// This round: byte-identical revert to the verified r12 117.99us build
// (k_qw -> k_uv -> k_delta).

// d_ws layout (floats)
#define WS_P    0        // [32 b][256 j]  (unused since r11 diag fusion)
#define WS_QWT  8192     // [256 d][256 j]
#define WS_PQ   73728    // [32 b][256 d]
#define WS_U    81920    // [8 h][256 e][256 j]
#define WS_V    606208   // [32 b][8 h][256 e]

typedef float vf4 __attribute__((ext_vector_type(4)));
__device__ __forceinline__ void nt_store4(float* p, float x, float y,
                                          float z, float w) {
  vf4 v; v.x = x; v.y = y; v.z = z; v.w = w;
  __builtin_nontemporal_store(v, (vf4*)p);
}

// ---------------------------------------------------------------------------
// K1: QwT (64 tile-blocks) + Pq (8 tile-blocks). 72 blocks x 256.
//   QwT[d][j] = sum_e Wq[d][e]*Qp[256+j][e]  — 32d x 32j tile per block
//   Pq[b][d]  = sum_e pe[b][e]*Wq[d][e]      — 32b x 32d tile per block
// Row-tiles staged in LDS (e-chunks of 128, stride 132 keeps f4 16B-aligned);
// each thread owns 4 outputs; f4 LDS reads, accumulate across chunks.
__global__ void __launch_bounds__(256)
k_qw(const float* __restrict__ Qp, const float* __restrict__ Wq,
     float* __restrict__ ws) {
  int bid = blockIdx.x, t = threadIdx.x;
  if (bid < 64) {                       // QwT tile
    __shared__ float wq_s[32][132];
    __shared__ float qp_s[32][132];
    int d0 = (bid >> 3) << 5, j0 = (bid & 7) << 5;
    int j = t & 31, dq = t >> 5;        // thread: j, d = d0+dq*4..+3
    float acc[4] = {0.f, 0.f, 0.f, 0.f};
    for (int ec = 0; ec < 256; ec += 128) {
      #pragma unroll
      for (int k = 0; k < 4; ++k) {     // stage both tiles, f4 coalesced
        int i = (k << 8) + t;           // 0..1023
        int r = i >> 5, c4 = i & 31;    // row, f4-col of 128-float chunk
        *(float4*)&wq_s[r][c4 << 2] =
            *(const float4*)(Wq + (size_t)(d0 + r) * 256 + ec + (c4 << 2));
        *(float4*)&qp_s[r][c4 << 2] =
            *(const float4*)(Qp + 65536 + (size_t)(j0 + r) * 256 + ec + (c4 << 2));
      }
      __syncthreads();
      #pragma unroll 8
      for (int e4 = 0; e4 < 32; ++e4) {
        float4 q = *(const float4*)&qp_s[j][e4 << 2];
        #pragma unroll
        for (int r = 0; r < 4; ++r) {
          float4 w = *(const float4*)&wq_s[(dq << 2) + r][e4 << 2];
          acc[r] += w.x * q.x + w.y * q.y + w.z * q.z + w.w * q.w;
        }
      }
      __syncthreads();
    }
    #pragma unroll
    for (int r = 0; r < 4; ++r)         // lanes j consecutive -> coalesced
      ws[WS_QWT + (size_t)(d0 + (dq << 2) + r) * 256 + j0 + j] = acc[r];
  } else {                              // Pq tile
    __shared__ float wq_s[32][132];
    __shared__ float pe_s[32][132];
    int d0 = (bid - 64) << 5;
    int b = t & 31, dq = t >> 5;        // thread: b, d = d0+dq*4..+3
    float acc[4] = {0.f, 0.f, 0.f, 0.f};
    for (int ec = 0; ec < 256; ec += 128) {
      #pragma unroll
      for (int k = 0; k < 4; ++k) {     // stage Wq tile
        int i = (k << 8) + t;
        int r = i >> 5, c4 = i & 31;
        *(float4*)&wq_s[r][c4 << 2] =
            *(const float4*)(Wq + (size_t)(d0 + r) * 256 + ec + (c4 << 2));
      }
      {                                 // pe analytic: (b2, 16 e's)/thread
        int b2 = t >> 3, e0 = (t & 7) << 4;
        #pragma unroll
        for (int k = 0; k < 16; ++k) {
          int e = e0 + k;               // within chunk
          int ge = ec + e;
          int k2 = ge & ~1;             // arange value 2k
          float div = expf((float)k2 * (-9.210340371976184f / 256.f));
          float a = (float)b2 * div;
          pe_s[b2][e] = (ge & 1) ? cosf(a) : sinf(a);
        }
      }
      __syncthreads();
      #pragma unroll 8
      for (int e4 = 0; e4 < 32; ++e4) {
        float4 p = *(const float4*)&pe_s[b][e4 << 2];
        #pragma unroll
        for (int r = 0; r < 4; ++r) {
          float4 w = *(const float4*)&wq_s[(dq << 2) + r][e4 << 2];
          acc[r] += w.x * p.x + w.y * p.y + w.z * p.z + w.w * p.w;
        }
      }
      __syncthreads();
    }
    #pragma unroll
    for (int r = 0; r < 4; ++r)         // 4 scalar stores/thread (1K/block)
      ws[WS_PQ + b * 256 + d0 + (dq << 2) + r] = acc[r];
  }
}

// ---------------------------------------------------------------------------
// K2: U[h][e][j] and V[b][h][e].  512 blocks x 256.  (r6 version, unchanged)
__global__ void __launch_bounds__(256)
k_uv(const float* __restrict__ Wk, const float* __restrict__ bq,
     float* __restrict__ ws) {
  int bid = blockIdx.x, t = threadIdx.x;
  if (bid < 256) {
    int h = bid >> 5, e0 = (bid & 31) << 3;
    __shared__ float wk_s[32][9];       // [d in h][e0..e0+7], +1 pad
    {
      int d = t >> 3, i = t & 7;        // 256 threads cover 32x8
      wk_s[d][i] = Wk[(size_t)(h * 32 + d) * 256 + e0 + i];
    }
    __syncthreads();
    float acc[8] = {0.f, 0.f, 0.f, 0.f, 0.f, 0.f, 0.f, 0.f};
    const float* __restrict__ Qw = ws + WS_QWT + t;
    #pragma unroll 4
    for (int d = 0; d < 32; ++d) {
      float q = Qw[((h << 5) + d) << 8];  // coalesced; wk_s broadcast
      #pragma unroll
      for (int i = 0; i < 8; ++i) acc[i] += wk_s[d][i] * q;
    }
    float* Uh = ws + WS_U + (h << 16) + (size_t)e0 * 256;
    #pragma unroll
    for (int i = 0; i < 8; ++i) Uh[(size_t)i * 256 + t] = acc[i];
  } else {
    int idx = bid - 256, b = idx >> 3, h = idx & 7;
    float acc = 0.f;
#pragma unroll 8
    for (int dd = 0; dd < 32; ++dd) {
      int d = h * 32 + dd;
      acc += (ws[WS_PQ + b * 256 + d] + bq[d]) * Wk[(size_t)d * 256 + t];
    }
    ws[WS_V + ((b << 3) + h) * 256 + t] = acc;
  }
}

// ---------------------------------------------------------------------------
// K3: delta + ALL output. 14592 blocks x 256. (r11 version; dead P store cut)
//   [0,256):        delta compute (b, j-tile32) + merge cols + atten diag
//   [256,2304):     new_state identity half (state cols 0..255)
//   [2304,14592):   atten static (one-hot l<256; zeros l>=256 minus diag f4s)
__global__ void __launch_bounds__(256)
k_delta(const float* __restrict__ state, const float* __restrict__ obs,
        float* __restrict__ ws, float* __restrict__ out) {
  int bid = blockIdx.x, t = threadIdx.x;
  if (bid < 256) {
    int b = bid >> 3, jt = (bid & 7) << 5;
    __shared__ float Xs[256][33];       // X[e][j], +1 pad -> <=2-way (free)
    __shared__ float Vs[2048];          // V[b][h][e] slice
    __shared__ float pd[8][8][32];      // [eg][h][j] partial sum X*w
    __shared__ float pw[8][8][32];      // [eg][h][j] partial sum w
    __shared__ float px[8][32];         // [eg][j]    partial sum X (reused)
    __shared__ float pfin[32];          // final p[b, jt+j]
    {                                   // stage: (es 0..31, jq 0..7) float4
      int es = t >> 3, jq = t & 7;
      const float* sp = state + (size_t)b * 131072 + 256 + jt + (jq << 2);
      const float* op = obs   + (size_t)b * 65536  + jt + (jq << 2);
      #pragma unroll
      for (int k = 0; k < 8; ++k) {
        int e = es + (k << 5);
        float4 s4 = *(const float4*)(sp + (size_t)e * 512);
        float4 o4 = *(const float4*)(op + (size_t)e * 256);
        float* xr = &Xs[e][jq << 2];
        xr[0] = s4.x - o4.x; xr[1] = s4.y - o4.y;
        xr[2] = s4.z - o4.z; xr[3] = s4.w - o4.w;
      }
      for (int i = t; i < 2048; i += 256) Vs[i] = ws[WS_V + (b << 11) + i];
    }
    __syncthreads();
    int j = t & 31, eg = t >> 5, e0 = eg << 5;
    {                                   // a_x partial (h-independent)
      float ax = 0.f;
      #pragma unroll
      for (int ei = 0; ei < 32; ++ei) ax += Xs[e0 + ei][j];
      px[eg][j] = ax;
    }
    const float* __restrict__ Ub = ws + WS_U + jt + j;
    #pragma unroll
    for (int h = 0; h < 8; ++h) {
      float dacc = 0.f, wacc = 0.f;
      const float* __restrict__ Uh = Ub + (h << 16) + (e0 << 8);
      const float* __restrict__ Vh = Vs + (h << 8) + e0;
      #pragma unroll 16
      for (int ei = 0; ei < 32; ++ei) {
        float w = Uh[ei << 8] + Vh[ei];
        dacc += Xs[e0 + ei][j] * w;
        wacc += w;
      }
      pd[eg][h][j] = dacc;
      pw[eg][h][j] = wacc;
    }
    __syncthreads();
    int h2 = t >> 5, j2 = t & 31;       // thread -> (h, j) for the merge
    float D = 0.f, W = 0.f, X = 0.f;
    #pragma unroll
    for (int g = 0; g < 8; ++g) {
      D += pd[g][h2][j2];
      W += pw[g][h2][j2];
      X += px[g][j2];
    }
    float delta = D - X * (1.f / 256.f) * W;
    float sig = 1.f / (1.f + __expf(-delta * 0.17677669529663687f)); // /sqrt(32)
    __syncthreads();
    px[h2][j2] = sig;                   // reuse px as [h][j] sigmoid buffer
    __syncthreads();
    if (t < 32) {
      float acc = 0.f;
      #pragma unroll
      for (int h = 0; h < 8; ++h) acc += px[h][t];
      float p = acc * 0.125f;
      pfin[t] = p;
      // atten diagonal: row l = 256+jt+t, f4 c1 = l>>2 (s=l), c2 = c1+64
      int l = 256 + jt + t;
      size_t rb = 4194304 + (size_t)((b << 9) + l) * 768;
      int c1 = l >> 2, pos = l & 3;
      float v1[4] = {0.f, 0.f, 0.f, 0.f}; v1[pos] = p;
      nt_store4(out + rb + (c1 << 2), v1[0], v1[1], v1[2], v1[3]);
      float v2[4] = {0.f, 0.f, 0.f, 0.f}; v2[pos] = 1.f - p;
      nt_store4(out + rb + ((c1 + 64) << 2), v2[0], v2[1], v2[2], v2[3]);
    }
    __syncthreads();
    // Fused merge: new_state[b, e, 256+jt+j] = o + p*X.
    {
      int eb = t >> 3, j0 = (t & 7) << 2;
      const float* op2 = obs + (size_t)b * 65536 + jt + j0;
      float p0 = pfin[j0], p1 = pfin[j0 + 1], p2 = pfin[j0 + 2], p3 = pfin[j0 + 3];
      float* orow = out + (size_t)b * 131072 + 256 + jt + j0;
      #pragma unroll
      for (int k = 0; k < 8; ++k) {
        int e = eb + (k << 5);
        float4 o4 = *(const float4*)(op2 + (size_t)e * 256);
        const float* xr = &Xs[e][j0];
        nt_store4(orow + (size_t)e * 512,
                  o4.x + p0 * xr[0], o4.y + p1 * xr[1],
                  o4.z + p2 * xr[2], o4.w + p3 * xr[3]);
      }
    }
  } else if (bid < 2304) {              // new_state[b,e,0..255] = state
    int row = ((bid - 256) << 2) | (t >> 6);  // row = b*256 + e
    int c = t & 63;                     // f4 col in lower half
    float4 sv = ((const float4*)(state + (size_t)row * 512))[c];
    nt_store4(out + (size_t)row * 512 + (c << 2), sv.x, sv.y, sv.z, sv.w);
  } else {                              // atten static, one float4 per thread
    int g4 = (bid - 2304) * 256 + t;    // 0..3145727
    int r = g4 / 192, c = g4 - r * 192; // r = b*512 + l
    int b = r >> 9, l = r & 511;
    int s0 = c << 2;
    if (l < 256) {                      // one-hot at s=l (P-independent)
      float v[4] = {0.f, 0.f, 0.f, 0.f};
      if (l >= s0 && l < s0 + 4) v[l - s0] = 1.0f;
      nt_store4(out + 4194304 + ((size_t)g4 << 2), v[0], v[1], v[2], v[3]);
    } else {                            // zeros, skipping the 2 diag f4s
      int c1 = l >> 2;                  // s=l f4 (64..127); c2 = c1+64
      if (c != c1 && c != c1 + 64)
        nt_store4(out + 4194304 + ((size_t)g4 << 2), 0.f, 0.f, 0.f, 0.f);
    }
  }
}

extern "C" void kernel_launch(void* const* d_in, const int* in_sizes, int n_in,
                              void* d_out, int out_size, void* d_ws, size_t ws_size,
                              hipStream_t stream) {
  const float *state = nullptr, *obs = nullptr, *Qp = nullptr;
  const float *Wq = nullptr, *Wk = nullptr, *bq = nullptr, *bk = nullptr;
  for (int i = 0; i < n_in; ++i) {
    int s = in_sizes[i];
    const float* p = (const float*)d_in[i];
    if      (s == 4194304) state = p;
    else if (s == 2097152) obs = p;
    else if (s == 131072)  Qp = p;
    else if (s == 65536)   { if (!Wq) Wq = p; else Wk = p; }
    else if (s == 256)     { if (!bq) bq = p; else bk = p; }
  }
  (void)bk;                             // cancels in the 2-way softmax
  float* out = (float*)d_out;
  float* ws  = (float*)d_ws;

  k_qw   <<<72,    256, 0, stream>>>(Qp, Wq, ws);
  k_uv   <<<512,   256, 0, stream>>>(Wk, bq, ws);
  k_delta<<<14592, 256, 0, stream>>>(state, obs, ws, out);
}